// Round 6
// baseline (984.330 us; speedup 1.0000x reference)
//
#include <hip/hip_runtime.h>
#include <stdint.h>

#define NPRIOR   15130
#define BATCH    32
#define NCLS     81
#define NCLS_OUT 80
#define NDET     200
#define CONF_T   0.05f
#define IOU_T    0.5f
#define CAND_CAP 1024
#define NGRP     5
#define GRP      16

// ---------------------------------------------------------------------------
// Kernel 0: zero the per-(b,c) candidate counters (ws is poisoned 0xAA).
// ---------------------------------------------------------------------------
__global__ __launch_bounds__(256) void zero_counters(unsigned int* __restrict__ counters, int n) {
    int i = blockIdx.x * 256 + threadIdx.x;
    if (i < n) counters[i] = 0u;
}

// ---------------------------------------------------------------------------
// Kernel A v6: 4-lanes-per-prior, NAMED-SCALAR register softmax.
// History: v1/v3 v[81]/thread and v5 v[21]/thread ALL got demoted to scratch
// (VGPR=48/24, +20-30MB scratch WRITE, latency-bound 300-450us) -- the
// compiler fails to promote local arrays here (rule #20). v2 re-read ->
// L2 thrash (390us). v4 LDS tile -> occupancy collapse (511us).
// v6 removes the array entirely: 21 NAMED scalars per lane (X-macro), all
// class offsets compile-time static. Nothing for SROA to fail on.
//   Layout: each prior owned by 4 lanes of one wave (slot=lane&15, h=lane>>4).
//   Lane-group h loads classes h*20 .. h*20+20 (21 values; boundary classes
//   20/40/60 duplicated: fine for max, exp recomputed identically, skipped
//   in sum/scatter).
//   - max: per-lane fmaxf chain + shfl_xor(16,32)   (exact, order-free)
//   - sum: wave relay h0(v0..v20)->h1(v1..v20)->h2->h3 reproduces the
//     reference's sequential __fadd_rn chain c=0..80 EXACTLY (v5 verified
//     this relay bit-exact on HW: absmax=0.0).
//   - scatter: lane h tests classes h*20+1..h*20+20 (covers 1..80 once);
//     e>CONF_T pre-test is superset of p>CONF_T (sum>=1); exact __fdiv_rn.
//   - loads clamped in-bounds for tail lanes; only stores/atomics guarded.
// ---------------------------------------------------------------------------
#define REP21(X) X(0) X(1) X(2) X(3) X(4) X(5) X(6) X(7) X(8) X(9) X(10) \
                 X(11) X(12) X(13) X(14) X(15) X(16) X(17) X(18) X(19) X(20)
#define REP20(X) X(1) X(2) X(3) X(4) X(5) X(6) X(7) X(8) X(9) X(10) \
                 X(11) X(12) X(13) X(14) X(15) X(16) X(17) X(18) X(19) X(20)

__global__ __launch_bounds__(256) void decode_softmax_scatter(
    const float* __restrict__ bboxes,     // (B,4,N)
    const float* __restrict__ scores,     // (B,81,N)
    const float* __restrict__ scale_xy_p, // (1,)
    const float* __restrict__ scale_wh_p, // (1,)
    const float* __restrict__ dboxes,     // (1,N,4)
    float* __restrict__ boxes_ltrb,       // (B,N,4)
    unsigned int* __restrict__ counters,  // (B*80)
    unsigned long long* __restrict__ cand_g) // (B*80, CAND_CAP)
{
    int tid  = threadIdx.x;
    int b    = blockIdx.y;
    int wave = tid >> 6;
    int lane = tid & 63;
    int slot = lane & 15;   // prior slot within wave
    int h    = lane >> 4;   // class-quarter 0..3
    int n    = blockIdx.x * 64 + wave * 16 + slot;
    bool active = (n < NPRIOR);
    int nc = active ? n : (NPRIOR - 1);   // clamped index: loads always in-bounds

    // ---- load this group's 21 classes into NAMED scalars ----
    const float* scp = scores + (size_t)b * NCLS * NPRIOR + (size_t)(h * 20) * NPRIOR + nc;
#define DECLV(k) float v##k;
    REP21(DECLV)
#undef DECLV
#define LOADV(k) v##k = scp[(size_t)(k) * NPRIOR];
    REP21(LOADV)
#undef LOADV

    // ---- decode boxes on h==3 lanes (independent of softmax values) ----
    if (h == 3) {
        float sx = scale_xy_p[0], sw = scale_wh_p[0];
        const float* bb = bboxes + (size_t)b * 4 * NPRIOR + nc;
        float bx = bb[0];
        float by = bb[NPRIOR];
        float bw = bb[2 * NPRIOR];
        float bh = bb[3 * NPRIOR];
        float dx = dboxes[nc * 4 + 0], dy = dboxes[nc * 4 + 1];
        float dw = dboxes[nc * 4 + 2], dh = dboxes[nc * 4 + 3];
        float x = __fadd_rn(__fmul_rn(__fmul_rn(bx, sx), dw), dx);
        float y = __fadd_rn(__fmul_rn(__fmul_rn(by, sx), dh), dy);
        float w = __fmul_rn(expf(__fmul_rn(bw, sw)), dw);
        float hh_ = __fmul_rn(expf(__fmul_rn(bh, sw)), dh);
        float hw = __fmul_rn(0.5f, w), hhh = __fmul_rn(0.5f, hh_);
        if (active) {
            float4 box;
            box.x = __fsub_rn(x, hw);
            box.y = __fsub_rn(y, hhh);
            box.z = __fadd_rn(x, hw);
            box.w = __fadd_rn(y, hhh);
            ((float4*)boxes_ltrb)[(size_t)b * NPRIOR + n] = box;
        }
    }

    // ---- max over all 81 classes: per-lane chain + 2 shuffles (exact) ----
    float mx = -INFINITY;
#define MAXV(k) mx = fmaxf(mx, v##k);
    REP21(MAXV)
#undef MAXV
    mx = fmaxf(mx, __shfl_xor(mx, 16, 64));
    mx = fmaxf(mx, __shfl_xor(mx, 32, 64));

    // ---- exp in place (same expression as reference) ----
#define EXPV(k) v##k = expf(__fsub_rn(v##k, mx));
    REP21(EXPV)
#undef EXPV

    // ---- serial exact sum: wave relay h0 -> h1 -> h2 -> h3 ----
    // h0 adds classes 0..20 (v0..v20); h1..h3 add v1..v20 (their v0 is the
    // previous group's v20 / boundary class, already counted).
    float cum = 0.f;
#define ADDV(k) cum = __fadd_rn(cum, v##k);
    if (h == 0) { REP21(ADDV) }
    cum = __shfl(cum, slot, 64);
    if (h == 1) { REP20(ADDV) }
    cum = __shfl(cum, slot + 16, 64);
    if (h == 2) { REP20(ADDV) }
    cum = __shfl(cum, slot + 32, 64);
    if (h == 3) { REP20(ADDV) }
    cum = __shfl(cum, slot + 48, 64);
#undef ADDV
    float sum = cum;  // total over classes 0..80, in all 4 lanes of the prior

    // ---- scatter candidates: lane h owns classes h*20+1 .. h*20+20 ----
    if (active) {
        unsigned int invn = 0xFFFFFFFFu - (unsigned int)n;
#define SCAT(k) { \
        float e = v##k; \
        if (e > CONF_T) { \
            float p = __fdiv_rn(e, sum); \
            if (p > CONF_T) { \
                unsigned int idx = (unsigned int)b * NCLS_OUT + (unsigned int)(h * 20 + (k) - 1); \
                unsigned int pos = atomicAdd(&counters[idx], 1u); \
                if (pos < CAND_CAP) { \
                    cand_g[(size_t)idx * CAND_CAP + pos] = \
                        ((unsigned long long)__float_as_uint(p) << 32) | (unsigned long long)invn; \
                } \
            } \
        } }
        REP20(SCAT)
#undef SCAT
    }
}

// ---------------------------------------------------------------------------
// Bitonic sort (descending) on P (power of 2) u64 keys in LDS, 256 threads.
// ---------------------------------------------------------------------------
__device__ inline void bitonic_desc(unsigned long long* keys, int P, int tid) {
    for (int k = 2; k <= P; k <<= 1) {
        for (int j = k >> 1; j > 0; j >>= 1) {
            for (int i = tid; i < P; i += 256) {
                int l = i ^ j;
                if (l > i) {
                    unsigned long long a = keys[i], b = keys[l];
                    bool desc = ((i & k) == 0);
                    if (desc ? (a < b) : (a > b)) {
                        keys[i] = b;
                        keys[l] = a;
                    }
                }
            }
            __syncthreads();
        }
    }
}

// ---------------------------------------------------------------------------
// Kernel B: per (b, class): sort candidates (desc score, asc index), take top
// 200, sequential-NMS via row bitmasks, write per-class scores & boxes.
// ---------------------------------------------------------------------------
__global__ __launch_bounds__(256) void nms_class(
    const unsigned int* __restrict__ counters,
    const unsigned long long* __restrict__ cand_g,
    const float* __restrict__ boxes_ltrb,
    float* __restrict__ cls_scores,  // (B,80,200)
    float* __restrict__ cls_boxes)   // (B,80,200,4)
{
    __shared__ unsigned long long cand[CAND_CAP];
    __shared__ float sbox[NDET][4];
    __shared__ float sscore[NDET];
    __shared__ unsigned long long rowm[NDET][4];
    __shared__ unsigned long long keepw[4];

    int tid = threadIdx.x;
    int b = blockIdx.y;
    int bc = b * NCLS_OUT + blockIdx.x;

    unsigned int cntu = counters[bc];
    int cnt = (cntu > CAND_CAP) ? CAND_CAP : (int)cntu;

    int P = 256;
    while (P < cnt) P <<= 1;  // <= CAND_CAP

    for (int i = tid; i < P; i += 256)
        cand[i] = (i < cnt) ? cand_g[(size_t)bc * CAND_CAP + i] : 0ull;
    __syncthreads();

    bitonic_desc(cand, P, tid);

    int m = cnt < NDET ? cnt : NDET;
    if (tid < m) {
        unsigned long long key = cand[tid];
        unsigned int n = 0xFFFFFFFFu - (unsigned int)(key & 0xFFFFFFFFull);
        sscore[tid] = __uint_as_float((unsigned int)(key >> 32));
        float4 bx = ((const float4*)boxes_ltrb)[(size_t)b * NPRIOR + n];
        sbox[tid][0] = bx.x;
        sbox[tid][1] = bx.y;
        sbox[tid][2] = bx.z;
        sbox[tid][3] = bx.w;
    }
    __syncthreads();

    // row bitmasks: row i -> bits j>i with iou(i,j) > IOU_T
    if (tid < m) {
        float l0 = sbox[tid][0], t0 = sbox[tid][1], r0 = sbox[tid][2], b0 = sbox[tid][3];
        float area0 = __fmul_rn(__fsub_rn(r0, l0), __fsub_rn(b0, t0));
        unsigned long long w0 = 0, w1 = 0, w2 = 0, w3 = 0;
        for (int j = tid + 1; j < m; ++j) {
            float lj = sbox[j][0], tj = sbox[j][1], rj = sbox[j][2], bj = sbox[j][3];
            float ltx = fmaxf(l0, lj), lty = fmaxf(t0, tj);
            float rbx = fminf(r0, rj), rby = fminf(b0, bj);
            float iw = fmaxf(__fsub_rn(rbx, ltx), 0.f);
            float ih = fmaxf(__fsub_rn(rby, lty), 0.f);
            float inter = __fmul_rn(iw, ih);
            float areaj = __fmul_rn(__fsub_rn(rj, lj), __fsub_rn(bj, tj));
            float den = __fsub_rn(__fadd_rn(area0, areaj), inter);
            float iou = __fdiv_rn(inter, den);
            if (iou > IOU_T) {
                if (j < 64) w0 |= 1ull << j;
                else if (j < 128) w1 |= 1ull << (j - 64);
                else if (j < 192) w2 |= 1ull << (j - 128);
                else w3 |= 1ull << (j - 192);
            }
        }
        rowm[tid][0] = w0;
        rowm[tid][1] = w1;
        rowm[tid][2] = w2;
        rowm[tid][3] = w3;
    }
    __syncthreads();

    if (tid == 0) {
        auto maskf = [](int t) -> unsigned long long {
            if (t <= 0) return 0ull;
            if (t >= 64) return ~0ull;
            return (1ull << t) - 1ull;
        };
        unsigned long long k0 = maskf(m), k1 = maskf(m - 64), k2 = maskf(m - 128), k3 = maskf(m - 192);
        for (int i = 0; i < m; ++i) {
            unsigned long long cur = (i < 64) ? k0 : (i < 128) ? k1 : (i < 192) ? k2 : k3;
            if ((cur >> (i & 63)) & 1ull) {
                k0 &= ~rowm[i][0];
                k1 &= ~rowm[i][1];
                k2 &= ~rowm[i][2];
                k3 &= ~rowm[i][3];
            }
        }
        keepw[0] = k0; keepw[1] = k1; keepw[2] = k2; keepw[3] = k3;
    }
    __syncthreads();

    if (tid < NDET) {
        float s = -1.0f;
        if (tid < m && ((keepw[tid >> 6] >> (tid & 63)) & 1ull)) s = sscore[tid];
        cls_scores[(size_t)bc * NDET + tid] = s;
        if (tid < m) {
            float4 bx;
            bx.x = sbox[tid][0]; bx.y = sbox[tid][1];
            bx.z = sbox[tid][2]; bx.w = sbox[tid][3];
            ((float4*)cls_boxes)[(size_t)bc * NDET + tid] = bx;
        }
    }
}

// ---------------------------------------------------------------------------
// Kernel C1: per (group of 16 classes, batch): collect valid (score>CONF_T),
// sort desc, emit top-200 keys (pad 0). Exact: any global-top-200 element is
// within its group's top-200.
// ---------------------------------------------------------------------------
__global__ __launch_bounds__(256) void topk_group(
    const float* __restrict__ cls_scores,
    unsigned long long* __restrict__ grp_keys) // (B, NGRP, 200)
{
    __shared__ unsigned long long keys[4096];
    __shared__ unsigned int cnt_s;

    int tid = threadIdx.x;
    int g = blockIdx.x, b = blockIdx.y;
    if (tid == 0) cnt_s = 0;
    __syncthreads();

    int base_e = g * GRP * NDET;
    const float* sp = cls_scores + (size_t)b * NCLS_OUT * NDET + base_e;
    for (int i = tid; i < GRP * NDET; i += 256) {
        float s = sp[i];
        if (s > CONF_T) {
            unsigned int pos = atomicAdd(&cnt_s, 1u);
            unsigned int e = (unsigned int)(base_e + i);
            keys[pos] = ((unsigned long long)__float_as_uint(s) << 32) |
                        (unsigned long long)(0xFFFFFFFFu - e);
        }
    }
    __syncthreads();
    int cnt = (int)cnt_s;  // <= 3200
    int P = 256;
    while (P < cnt) P <<= 1;  // <= 4096
    for (int i = tid; i < P; i += 256)
        if (i >= cnt) keys[i] = 0ull;
    __syncthreads();

    bitonic_desc(keys, P, tid);

    if (tid < NDET)
        grp_keys[((size_t)b * NGRP + g) * NDET + tid] = (tid < cnt) ? keys[tid] : 0ull;
}

// ---------------------------------------------------------------------------
// Kernel C2: per batch: merge 5*200 group keys, sort, emit final top-200.
// ---------------------------------------------------------------------------
__global__ __launch_bounds__(256) void final_topk(
    const unsigned long long* __restrict__ grp_keys,
    const float* __restrict__ cls_boxes,
    float* __restrict__ out)
{
    __shared__ unsigned long long keys[1024];
    __shared__ unsigned int cnt_s;

    int tid = threadIdx.x, b = blockIdx.x;
    if (tid == 0) cnt_s = 0;
    __syncthreads();

    for (int i = tid; i < NGRP * NDET; i += 256) {
        unsigned long long k = grp_keys[(size_t)b * NGRP * NDET + i];
        if (k != 0ull) keys[atomicAdd(&cnt_s, 1u)] = k;
    }
    __syncthreads();
    int cnt = (int)cnt_s;  // <= 1000
    int P = 256;
    while (P < cnt) P <<= 1;  // <= 1024
    for (int i = tid; i < P; i += 256)
        if (i >= cnt) keys[i] = 0ull;
    __syncthreads();

    bitonic_desc(keys, P, tid);

    if (tid < NDET) {
        float4 bx = make_float4(0.f, 0.f, 0.f, 0.f);
        float lab = 0.f, sc = 0.f;
        if (tid < cnt) {
            unsigned long long k = keys[tid];
            unsigned int e = 0xFFFFFFFFu - (unsigned int)(k & 0xFFFFFFFFull);
            sc = __uint_as_float((unsigned int)(k >> 32));
            unsigned int c0 = e / NDET;
            bx = ((const float4*)cls_boxes)[(size_t)b * NCLS_OUT * NDET + e];
            lab = (float)(c0 + 1);
        }
        float* fb = out;                                // (B,200,4)
        float* fl = out + (size_t)BATCH * NDET * 4;     // (B,200)
        float* fs = fl + (size_t)BATCH * NDET;          // (B,200)
        ((float4*)fb)[b * NDET + tid] = bx;
        fl[b * NDET + tid] = lab;
        fs[b * NDET + tid] = sc;
    }
}

// ---------------------------------------------------------------------------
extern "C" void kernel_launch(void* const* d_in, const int* in_sizes, int n_in,
                              void* d_out, int out_size, void* d_ws, size_t ws_size,
                              hipStream_t stream) {
    const float* bboxes = (const float*)d_in[0];
    const float* scores = (const float*)d_in[1];
    const float* sxy    = (const float*)d_in[2];
    const float* swh    = (const float*)d_in[3];
    const float* dbx    = (const float*)d_in[4];
    float* out = (float*)d_out;

    char* ws = (char*)d_ws;
    size_t off = 0;
    auto alloc = [&](size_t bytes) -> char* {
        char* p = ws + off;
        off += (bytes + 255) & ~(size_t)255;
        return p;
    };
    float* boxes_ltrb            = (float*)alloc((size_t)BATCH * NPRIOR * 4 * 4);
    unsigned int* counters       = (unsigned int*)alloc((size_t)BATCH * NCLS_OUT * 4);
    unsigned long long* cand_g   = (unsigned long long*)alloc((size_t)BATCH * NCLS_OUT * CAND_CAP * 8);
    float* cls_scores            = (float*)alloc((size_t)BATCH * NCLS_OUT * NDET * 4);
    float* cls_boxes             = (float*)alloc((size_t)BATCH * NCLS_OUT * NDET * 4 * 4);
    unsigned long long* grp_keys = (unsigned long long*)alloc((size_t)BATCH * NGRP * NDET * 8);

    int ncounters = BATCH * NCLS_OUT;
    zero_counters<<<(ncounters + 255) / 256, 256, 0, stream>>>(counters, ncounters);

    // 64 priors per block (4 waves x 16 slots)
    dim3 gridA((NPRIOR + 63) / 64, BATCH);
    decode_softmax_scatter<<<gridA, 256, 0, stream>>>(
        bboxes, scores, sxy, swh, dbx, boxes_ltrb, counters, cand_g);

    dim3 gridB(NCLS_OUT, BATCH);
    nms_class<<<gridB, 256, 0, stream>>>(counters, cand_g, boxes_ltrb, cls_scores, cls_boxes);

    dim3 gridC1(NGRP, BATCH);
    topk_group<<<gridC1, 256, 0, stream>>>(cls_scores, grp_keys);

    final_topk<<<BATCH, 256, 0, stream>>>(grp_keys, cls_boxes, out);
}

// Round 7
// 920.535 us; speedup vs baseline: 1.0693x; 1.0693x over previous
//
#include <hip/hip_runtime.h>
#include <stdint.h>

#define NPRIOR   15130
#define BATCH    32
#define NCLS     81
#define NCLS_OUT 80
#define NDET     200
#define CONF_T   0.05f
#define IOU_T    0.5f
#define CAND_CAP 1024
#define NGRP     5
#define GRP      16
#define PPB      64    // priors per block in kernel A
#define ROWW     68    // LDS row stride in words: 2-way banks only, 272B = 16B-aligned rows

// ---------------------------------------------------------------------------
// Kernel 0: zero the per-(b,c) candidate counters (ws is poisoned 0xAA).
// ---------------------------------------------------------------------------
__global__ __launch_bounds__(256) void zero_counters(unsigned int* __restrict__ counters, int n) {
    int i = blockIdx.x * 256 + threadIdx.x;
    if (i < n) counters[i] = 0u;
}

// ---------------------------------------------------------------------------
// Kernel A v7: LDS tile + 4-lanes-per-prior, nothing kept live.
// Evidence so far: any >=20 live floats/lane spills regardless of expression
// (v1/v3 array, v5 array, v6 named scalars: VGPR 24-48, +20MB scratch WRITE,
// 300-473us). Global re-read thrashes L2 (v2, 390us). LDS tile works but v4
// executed it badly (41.5KB tile -> 3 blocks/CU, half threads idle, 511us).
// v7: 64-prior tile (81x68 words = 22KB -> 7 blocks/CU, 87% occ). Each prior
// owned by 4 lanes (slot=lane&15, h=lane>>4); lane h scans classes
// {0..20 | 21..40 | 41..60 | 61..80} straight out of LDS (static offsets,
// values never live across more than one op). Row stride 68: class-walk is a
// uniform 2-way bank alias (free, m136), rows 16B-aligned.
//   - max: per-lane fmaxf chain + shfl_xor(16,32)        (exact, order-free)
//   - exp: in place in LDS (own cells only -> no race, no barrier)
//   - sum: wave relay h0->h1->h2->h3, each stage re-reads its e's from LDS;
//     reproduces the reference's sequential __fadd_rn chain c=0..80 exactly
//     (relay pattern HW-verified bit-exact in v5 AND v6: absmax=0.0).
//   - scatter: flags from pass2 (e>CONF_T superset of p>CONF_T since sum>=1);
//     exact p=__fdiv_rn(e,sum) decides.
// ---------------------------------------------------------------------------
__global__ __launch_bounds__(256) void decode_softmax_scatter(
    const float* __restrict__ bboxes,     // (B,4,N)
    const float* __restrict__ scores,     // (B,81,N)
    const float* __restrict__ scale_xy_p, // (1,)
    const float* __restrict__ scale_wh_p, // (1,)
    const float* __restrict__ dboxes,     // (1,N,4)
    float* __restrict__ boxes_ltrb,       // (B,N,4)
    unsigned int* __restrict__ counters,  // (B*80)
    unsigned long long* __restrict__ cand_g) // (B*80, CAND_CAP)
{
    __shared__ float lds[NCLS * ROWW];    // 81*68*4 = 22032 B

    int tid = threadIdx.x;
    int b = blockIdx.y;
    int base = blockIdx.x * PPB;
    int nvalid = NPRIOR - base;
    if (nvalid > PPB) nvalid = PPB;

    const float* sb = scores + (size_t)b * NCLS * NPRIOR + base;

    // ---- stage the 81x64 score tile (float2: rows are 8B-aligned since
    //      NPRIOR and base are even; full-tile blocks only) ----
    if (nvalid == PPB) {
        for (int i = tid; i < NCLS * (PPB / 2); i += 256) {  // 81*32 = 2592
            int c = i >> 5, q = i & 31;
            float2 v = *(const float2*)(sb + (size_t)c * NPRIOR + q * 2);
            *(float2*)&lds[c * ROWW + q * 2] = v;
        }
    } else {
        // tail block: scalar loads, zero-fill invalid columns (keeps exp sane)
        for (int i = tid; i < NCLS * PPB; i += 256) {
            int c = i >> 6, w = i & 63;
            lds[c * ROWW + w] = (w < nvalid) ? sb[(size_t)c * NPRIOR + w] : 0.0f;
        }
    }

    int wave = tid >> 6, lane = tid & 63, slot = lane & 15, h = lane >> 4;
    int sg = wave * 16 + slot;          // prior slot within block, 0..63
    int n = base + sg;
    bool active = (sg < nvalid);
    int cbase = h * 20;                 // h0 also owns class 0

    // ---- decode boxes on h==0 lanes (global-only; overlap with staging) ----
    if (h == 0 && active) {
        float sx = scale_xy_p[0], sw = scale_wh_p[0];
        const float* bb = bboxes + (size_t)b * 4 * NPRIOR + n;
        float bx = bb[0];
        float by = bb[NPRIOR];
        float bw = bb[2 * NPRIOR];
        float bh = bb[3 * NPRIOR];
        float dx = dboxes[n * 4 + 0], dy = dboxes[n * 4 + 1];
        float dw = dboxes[n * 4 + 2], dh = dboxes[n * 4 + 3];
        float x = __fadd_rn(__fmul_rn(__fmul_rn(bx, sx), dw), dx);
        float y = __fadd_rn(__fmul_rn(__fmul_rn(by, sx), dh), dy);
        float w  = __fmul_rn(expf(__fmul_rn(bw, sw)), dw);
        float hg = __fmul_rn(expf(__fmul_rn(bh, sw)), dh);
        float hw = __fmul_rn(0.5f, w), hh2 = __fmul_rn(0.5f, hg);
        float4 box;
        box.x = __fsub_rn(x, hw);
        box.y = __fsub_rn(y, hh2);
        box.z = __fadd_rn(x, hw);
        box.w = __fadd_rn(y, hh2);
        ((float4*)boxes_ltrb)[(size_t)b * NPRIOR + n] = box;
    }

    __syncthreads();

    const int rb = cbase * ROWW + sg;   // LDS word index of (class cbase, this prior)

    // ---- pass 1: max (per-lane chain + 2 shuffles; exact) ----
    float mx = -INFINITY;
    if (h == 0) mx = fmaxf(mx, lds[sg]);            // class 0
#pragma unroll
    for (int k = 1; k <= 20; ++k)
        mx = fmaxf(mx, lds[rb + k * ROWW]);
    mx = fmaxf(mx, __shfl_xor(mx, 16, 64));
    mx = fmaxf(mx, __shfl_xor(mx, 32, 64));

    // ---- pass 2a: exp in place (own cells only) + candidate flags ----
    unsigned int flags = 0;
    if (h == 0) lds[sg] = expf(__fsub_rn(lds[sg], mx));
#pragma unroll
    for (int k = 1; k <= 20; ++k) {
        float e = expf(__fsub_rn(lds[rb + k * ROWW], mx));
        lds[rb + k * ROWW] = e;
        if (e > CONF_T) flags |= (1u << k);
    }

    // ---- pass 2b: exact sequential sum via wave relay (LDS-sourced) ----
    float cum = 0.f;
    if (h == 0) {
        cum = __fadd_rn(cum, lds[sg]);              // class 0
#pragma unroll
        for (int k = 1; k <= 20; ++k) cum = __fadd_rn(cum, lds[rb + k * ROWW]);
    }
    cum = __shfl(cum, slot, 64);
    if (h == 1) {
#pragma unroll
        for (int k = 1; k <= 20; ++k) cum = __fadd_rn(cum, lds[rb + k * ROWW]);
    }
    cum = __shfl(cum, 16 + slot, 64);
    if (h == 2) {
#pragma unroll
        for (int k = 1; k <= 20; ++k) cum = __fadd_rn(cum, lds[rb + k * ROWW]);
    }
    cum = __shfl(cum, 32 + slot, 64);
    if (h == 3) {
#pragma unroll
        for (int k = 1; k <= 20; ++k) cum = __fadd_rn(cum, lds[rb + k * ROWW]);
    }
    cum = __shfl(cum, 48 + slot, 64);
    float sum = cum;  // total over classes 0..80, all 4 owner lanes

    // ---- pass 3: sparse scatter (lane h owns classes cbase+1..cbase+20) ----
    if (active && flags) {
        unsigned int invn = 0xFFFFFFFFu - (unsigned int)n;
        unsigned int f = flags;
        while (f) {
            int k = __ffs(f) - 1;
            f &= f - 1;
            float e = lds[rb + k * ROWW];
            float p = __fdiv_rn(e, sum);
            if (p > CONF_T) {
                int c = cbase + k;
                unsigned int idx = (unsigned int)b * NCLS_OUT + (unsigned int)(c - 1);
                unsigned int pos = atomicAdd(&counters[idx], 1u);
                if (pos < CAND_CAP) {
                    cand_g[(size_t)idx * CAND_CAP + pos] =
                        ((unsigned long long)__float_as_uint(p) << 32) | (unsigned long long)invn;
                }
            }
        }
    }
}

// ---------------------------------------------------------------------------
// Bitonic sort (descending) on P (power of 2) u64 keys in LDS, 256 threads.
// ---------------------------------------------------------------------------
__device__ inline void bitonic_desc(unsigned long long* keys, int P, int tid) {
    for (int k = 2; k <= P; k <<= 1) {
        for (int j = k >> 1; j > 0; j >>= 1) {
            for (int i = tid; i < P; i += 256) {
                int l = i ^ j;
                if (l > i) {
                    unsigned long long a = keys[i], b = keys[l];
                    bool desc = ((i & k) == 0);
                    if (desc ? (a < b) : (a > b)) {
                        keys[i] = b;
                        keys[l] = a;
                    }
                }
            }
            __syncthreads();
        }
    }
}

// ---------------------------------------------------------------------------
// Kernel B: per (b, class): sort candidates (desc score, asc index), take top
// 200, NMS via row bitmasks. v7: the greedy scan is now a 4-lane parallel
// scan with row prefetch (was a serial tid==0 loop: ~200-deep LDS-latency
// chain). Semantics identical: iterate i ascending; if i still kept, clear
// rowm[i] bits from keep.
// ---------------------------------------------------------------------------
__global__ __launch_bounds__(256) void nms_class(
    const unsigned int* __restrict__ counters,
    const unsigned long long* __restrict__ cand_g,
    const float* __restrict__ boxes_ltrb,
    float* __restrict__ cls_scores,  // (B,80,200)
    float* __restrict__ cls_boxes)   // (B,80,200,4)
{
    __shared__ unsigned long long cand[CAND_CAP];
    __shared__ float sbox[NDET][4];
    __shared__ float sscore[NDET];
    __shared__ unsigned long long rowm[NDET][4];
    __shared__ unsigned long long keepw[4];

    int tid = threadIdx.x;
    int b = blockIdx.y;
    int bc = b * NCLS_OUT + blockIdx.x;

    unsigned int cntu = counters[bc];
    int cnt = (cntu > CAND_CAP) ? CAND_CAP : (int)cntu;

    int P = 256;
    while (P < cnt) P <<= 1;  // <= CAND_CAP

    for (int i = tid; i < P; i += 256)
        cand[i] = (i < cnt) ? cand_g[(size_t)bc * CAND_CAP + i] : 0ull;
    __syncthreads();

    bitonic_desc(cand, P, tid);

    int m = cnt < NDET ? cnt : NDET;
    if (tid < m) {
        unsigned long long key = cand[tid];
        unsigned int n = 0xFFFFFFFFu - (unsigned int)(key & 0xFFFFFFFFull);
        sscore[tid] = __uint_as_float((unsigned int)(key >> 32));
        float4 bx = ((const float4*)boxes_ltrb)[(size_t)b * NPRIOR + n];
        sbox[tid][0] = bx.x;
        sbox[tid][1] = bx.y;
        sbox[tid][2] = bx.z;
        sbox[tid][3] = bx.w;
    }
    __syncthreads();

    // row bitmasks: row i -> bits j>i with iou(i,j) > IOU_T
    if (tid < m) {
        float l0 = sbox[tid][0], t0 = sbox[tid][1], r0 = sbox[tid][2], b0 = sbox[tid][3];
        float area0 = __fmul_rn(__fsub_rn(r0, l0), __fsub_rn(b0, t0));
        unsigned long long w0 = 0, w1 = 0, w2 = 0, w3 = 0;
        for (int j = tid + 1; j < m; ++j) {
            float lj = sbox[j][0], tj = sbox[j][1], rj = sbox[j][2], bj = sbox[j][3];
            float ltx = fmaxf(l0, lj), lty = fmaxf(t0, tj);
            float rbx = fminf(r0, rj), rby = fminf(b0, bj);
            float iw = fmaxf(__fsub_rn(rbx, ltx), 0.f);
            float ih = fmaxf(__fsub_rn(rby, lty), 0.f);
            float inter = __fmul_rn(iw, ih);
            float areaj = __fmul_rn(__fsub_rn(rj, lj), __fsub_rn(bj, tj));
            float den = __fsub_rn(__fadd_rn(area0, areaj), inter);
            float iou = __fdiv_rn(inter, den);
            if (iou > IOU_T) {
                if (j < 64) w0 |= 1ull << j;
                else if (j < 128) w1 |= 1ull << (j - 64);
                else if (j < 192) w2 |= 1ull << (j - 128);
                else w3 |= 1ull << (j - 192);
            }
        }
        rowm[tid][0] = w0;
        rowm[tid][1] = w1;
        rowm[tid][2] = w2;
        rowm[tid][3] = w3;
    }
    __syncthreads();

    // greedy scan, 4-lane parallel with prefetch (wave 0)
    if (tid < 64) {
        int lw = tid & 3;  // keep-word owned by lanes 0..3
        auto maskf = [](int t) -> unsigned long long {
            if (t <= 0) return 0ull;
            if (t >= 64) return ~0ull;
            return (1ull << t) - 1ull;
        };
        unsigned long long keep = 0ull;
        if (tid < 4) keep = maskf(m - lw * 64);
        unsigned long long nxt = 0ull;
        if (tid < 4 && m > 0) nxt = rowm[0][lw];
        for (int i = 0; i < m; ++i) {
            int ow = i >> 6;
            int bit = (int)((keep >> (i & 63)) & 1ull);
            bit = __shfl(bit, ow, 64);                  // broadcast from owner lane
            unsigned long long cur = nxt;
            if (tid < 4 && i + 1 < m) nxt = rowm[i + 1][lw];  // prefetch next row
            if (bit) keep &= ~cur;
        }
        if (tid < 4) keepw[lw] = keep;
    }
    __syncthreads();

    if (tid < NDET) {
        float s = -1.0f;
        if (tid < m && ((keepw[tid >> 6] >> (tid & 63)) & 1ull)) s = sscore[tid];
        cls_scores[(size_t)bc * NDET + tid] = s;
        if (tid < m) {
            float4 bx;
            bx.x = sbox[tid][0]; bx.y = sbox[tid][1];
            bx.z = sbox[tid][2]; bx.w = sbox[tid][3];
            ((float4*)cls_boxes)[(size_t)bc * NDET + tid] = bx;
        }
    }
}

// ---------------------------------------------------------------------------
// Kernel C1: per (group of 16 classes, batch): collect valid (score>CONF_T),
// sort desc, emit top-200 keys (pad 0). Exact: any global-top-200 element is
// within its group's top-200.
// ---------------------------------------------------------------------------
__global__ __launch_bounds__(256) void topk_group(
    const float* __restrict__ cls_scores,
    unsigned long long* __restrict__ grp_keys) // (B, NGRP, 200)
{
    __shared__ unsigned long long keys[4096];
    __shared__ unsigned int cnt_s;

    int tid = threadIdx.x;
    int g = blockIdx.x, b = blockIdx.y;
    if (tid == 0) cnt_s = 0;
    __syncthreads();

    int base_e = g * GRP * NDET;
    const float* sp = cls_scores + (size_t)b * NCLS_OUT * NDET + base_e;
    for (int i = tid; i < GRP * NDET; i += 256) {
        float s = sp[i];
        if (s > CONF_T) {
            unsigned int pos = atomicAdd(&cnt_s, 1u);
            unsigned int e = (unsigned int)(base_e + i);
            keys[pos] = ((unsigned long long)__float_as_uint(s) << 32) |
                        (unsigned long long)(0xFFFFFFFFu - e);
        }
    }
    __syncthreads();
    int cnt = (int)cnt_s;  // <= 3200
    int P = 256;
    while (P < cnt) P <<= 1;  // <= 4096
    for (int i = tid; i < P; i += 256)
        if (i >= cnt) keys[i] = 0ull;
    __syncthreads();

    bitonic_desc(keys, P, tid);

    if (tid < NDET)
        grp_keys[((size_t)b * NGRP + g) * NDET + tid] = (tid < cnt) ? keys[tid] : 0ull;
}

// ---------------------------------------------------------------------------
// Kernel C2: per batch: merge 5*200 group keys, sort, emit final top-200.
// ---------------------------------------------------------------------------
__global__ __launch_bounds__(256) void final_topk(
    const unsigned long long* __restrict__ grp_keys,
    const float* __restrict__ cls_boxes,
    float* __restrict__ out)
{
    __shared__ unsigned long long keys[1024];
    __shared__ unsigned int cnt_s;

    int tid = threadIdx.x, b = blockIdx.x;
    if (tid == 0) cnt_s = 0;
    __syncthreads();

    for (int i = tid; i < NGRP * NDET; i += 256) {
        unsigned long long k = grp_keys[(size_t)b * NGRP * NDET + i];
        if (k != 0ull) keys[atomicAdd(&cnt_s, 1u)] = k;
    }
    __syncthreads();
    int cnt = (int)cnt_s;  // <= 1000
    int P = 256;
    while (P < cnt) P <<= 1;  // <= 1024
    for (int i = tid; i < P; i += 256)
        if (i >= cnt) keys[i] = 0ull;
    __syncthreads();

    bitonic_desc(keys, P, tid);

    if (tid < NDET) {
        float4 bx = make_float4(0.f, 0.f, 0.f, 0.f);
        float lab = 0.f, sc = 0.f;
        if (tid < cnt) {
            unsigned long long k = keys[tid];
            unsigned int e = 0xFFFFFFFFu - (unsigned int)(k & 0xFFFFFFFFull);
            sc = __uint_as_float((unsigned int)(k >> 32));
            unsigned int c0 = e / NDET;
            bx = ((const float4*)cls_boxes)[(size_t)b * NCLS_OUT * NDET + e];
            lab = (float)(c0 + 1);
        }
        float* fb = out;                                // (B,200,4)
        float* fl = out + (size_t)BATCH * NDET * 4;     // (B,200)
        float* fs = fl + (size_t)BATCH * NDET;          // (B,200)
        ((float4*)fb)[b * NDET + tid] = bx;
        fl[b * NDET + tid] = lab;
        fs[b * NDET + tid] = sc;
    }
}

// ---------------------------------------------------------------------------
extern "C" void kernel_launch(void* const* d_in, const int* in_sizes, int n_in,
                              void* d_out, int out_size, void* d_ws, size_t ws_size,
                              hipStream_t stream) {
    const float* bboxes = (const float*)d_in[0];
    const float* scores = (const float*)d_in[1];
    const float* sxy    = (const float*)d_in[2];
    const float* swh    = (const float*)d_in[3];
    const float* dbx    = (const float*)d_in[4];
    float* out = (float*)d_out;

    char* ws = (char*)d_ws;
    size_t off = 0;
    auto alloc = [&](size_t bytes) -> char* {
        char* p = ws + off;
        off += (bytes + 255) & ~(size_t)255;
        return p;
    };
    float* boxes_ltrb            = (float*)alloc((size_t)BATCH * NPRIOR * 4 * 4);
    unsigned int* counters       = (unsigned int*)alloc((size_t)BATCH * NCLS_OUT * 4);
    unsigned long long* cand_g   = (unsigned long long*)alloc((size_t)BATCH * NCLS_OUT * CAND_CAP * 8);
    float* cls_scores            = (float*)alloc((size_t)BATCH * NCLS_OUT * NDET * 4);
    float* cls_boxes             = (float*)alloc((size_t)BATCH * NCLS_OUT * NDET * 4 * 4);
    unsigned long long* grp_keys = (unsigned long long*)alloc((size_t)BATCH * NGRP * NDET * 8);

    int ncounters = BATCH * NCLS_OUT;
    zero_counters<<<(ncounters + 255) / 256, 256, 0, stream>>>(counters, ncounters);

    dim3 gridA((NPRIOR + PPB - 1) / PPB, BATCH);   // 237 x 32
    decode_softmax_scatter<<<gridA, 256, 0, stream>>>(
        bboxes, scores, sxy, swh, dbx, boxes_ltrb, counters, cand_g);

    dim3 gridB(NCLS_OUT, BATCH);
    nms_class<<<gridB, 256, 0, stream>>>(counters, cand_g, boxes_ltrb, cls_scores, cls_boxes);

    dim3 gridC1(NGRP, BATCH);
    topk_group<<<gridC1, 256, 0, stream>>>(cls_scores, grp_keys);

    final_topk<<<BATCH, 256, 0, stream>>>(grp_keys, cls_boxes, out);
}